// Round 1
// baseline (144.199 us; speedup 1.0000x reference)
//
#include <hip/hip_runtime.h>

// One thread per row. Entirely register-resident: attention-1 (16x16 scalar
// attention), fused 16->64 sigmoid MLP + 64->8 linear (x1[64] never stored),
// attention-2 (8x8), final softmax + dot with x[8:16].
//
// Key identities used:
//   Alpha[i,j] = (k*q) * x_i * x_j, so row-softmax max = max(c*xmax, c*xmin)
//   where c = k*q*x_i  (xmax/xmin computed once per row).
//   O[j] = v * sum_i x_i * softmax_row_i(j)  -> accumulate with w = v*x_i/s_i.

__device__ __forceinline__ float rcpf(float a) { return __builtin_amdgcn_rcpf(a); }

__global__ __launch_bounds__(256) void fused_attn_mlp(
    const float* __restrict__ x,
    const float* __restrict__ wq,
    const float* __restrict__ wk,
    const float* __restrict__ wv,
    const float* __restrict__ Wh,
    const float* __restrict__ bh,
    const float* __restrict__ Wo,
    const float* __restrict__ bo,
    float* __restrict__ out,
    int B)
{
    const int b = blockIdx.x * blockDim.x + threadIdx.x;
    if (b >= B) return;

    // ---- load x row: 16 floats = 4x float4 (64B/lane, coalesced) ----
    float xv[16];
    const float4* xr = reinterpret_cast<const float4*>(x) + (size_t)b * 4;
    float4 a0 = xr[0], a1 = xr[1], a2 = xr[2], a3 = xr[3];
    xv[0] = a0.x; xv[1] = a0.y; xv[2]  = a0.z; xv[3]  = a0.w;
    xv[4] = a1.x; xv[5] = a1.y; xv[6]  = a1.z; xv[7]  = a1.w;
    xv[8] = a2.x; xv[9] = a2.y; xv[10] = a2.z; xv[11] = a2.w;
    xv[12] = a3.x; xv[13] = a3.y; xv[14] = a3.z; xv[15] = a3.w;

    // ---- attention block 1 (D=16, scalar q/k/v) ----
    const float kq1 = wk[0] * wq[0];
    const float v1  = wv[0];

    float xmx = xv[0], xmn = xv[0];
    #pragma unroll
    for (int i = 1; i < 16; ++i) { xmx = fmaxf(xmx, xv[i]); xmn = fminf(xmn, xv[i]); }

    float o1[16];
    #pragma unroll
    for (int j = 0; j < 16; ++j) o1[j] = 0.f;

    #pragma unroll
    for (int i = 0; i < 16; ++i) {
        const float c = kq1 * xv[i];
        const float m = fmaxf(c * xmx, c * xmn);  // exact row max (attained)
        float e[16], s = 0.f;
        #pragma unroll
        for (int j = 0; j < 16; ++j) { e[j] = __expf(c * xv[j] - m); s += e[j]; }
        const float w = v1 * xv[i] * rcpf(s);
        #pragma unroll
        for (int j = 0; j < 16; ++j) o1[j] += w * e[j];
    }

    // ---- hidden (16->64 + sigmoid) fused with output (64->8) ----
    // Weight addresses are wave-uniform -> compiler emits s_load (SMEM pipe).
    float x2[8];
    #pragma unroll
    for (int o = 0; o < 8; ++o) x2[o] = bo[o];

    #pragma unroll 8
    for (int h = 0; h < 64; ++h) {
        float acc = bh[h];
        #pragma unroll
        for (int i = 0; i < 16; ++i) acc += o1[i] * Wh[h * 16 + i];
        const float sg = rcpf(1.f + __expf(-acc));   // sigmoid
        #pragma unroll
        for (int o = 0; o < 8; ++o) x2[o] += Wo[o * 64 + h] * sg;
    }

    // ---- attention block 2 (D=8) ----
    const float kq2 = wk[1] * wq[1];
    const float v2  = wv[1];

    float ymx = x2[0], ymn = x2[0];
    #pragma unroll
    for (int i = 1; i < 8; ++i) { ymx = fmaxf(ymx, x2[i]); ymn = fminf(ymn, x2[i]); }

    float o2[8];
    #pragma unroll
    for (int j = 0; j < 8; ++j) o2[j] = 0.f;

    #pragma unroll
    for (int i = 0; i < 8; ++i) {
        const float c = kq2 * x2[i];
        const float m = fmaxf(c * ymx, c * ymn);
        float e[8], s = 0.f;
        #pragma unroll
        for (int j = 0; j < 8; ++j) { e[j] = __expf(c * x2[j] - m); s += e[j]; }
        const float w = v2 * x2[i] * rcpf(s);
        #pragma unroll
        for (int j = 0; j < 8; ++j) o2[j] += w * e[j];
    }

    // ---- softmax(o2) then dot with x[8:16] ----
    float m2 = o2[0];
    #pragma unroll
    for (int i = 1; i < 8; ++i) m2 = fmaxf(m2, o2[i]);
    float s2 = 0.f, dot = 0.f;
    #pragma unroll
    for (int i = 0; i < 8; ++i) {
        const float e = __expf(o2[i] - m2);
        s2 += e;
        dot += xv[8 + i] * e;
    }
    out[b] = dot * rcpf(s2);
}

extern "C" void kernel_launch(void* const* d_in, const int* in_sizes, int n_in,
                              void* d_out, int out_size, void* d_ws, size_t ws_size,
                              hipStream_t stream) {
    const float* x  = (const float*)d_in[0];
    const float* wq = (const float*)d_in[1];
    const float* wk = (const float*)d_in[2];
    const float* wv = (const float*)d_in[3];
    const float* Wh = (const float*)d_in[4];
    const float* bh = (const float*)d_in[5];
    const float* Wo = (const float*)d_in[6];
    const float* bo = (const float*)d_in[7];
    float* out = (float*)d_out;

    const int B = in_sizes[0] / 16;
    const int block = 256;
    const int grid = (B + block - 1) / block;
    fused_attn_mlp<<<grid, block, 0, stream>>>(x, wq, wk, wv, Wh, bh, Wo, bo, out, B);
}

// Round 2
// 132.276 us; speedup vs baseline: 1.0901x; 1.0901x over previous
//
#include <hip/hip_runtime.h>

// One thread per row, fully register-resident math, packed-fp32 (v_pk_fma_f32)
// inner loops, exp2-domain softmax/sigmoid (v_exp_f32 is natively 2^x),
// weights staged once per block into LDS (wave-uniform broadcast reads ->
// VGPR pairs -> packed MLP FMAs; kills repeated in-loop s_load stalls).
//
// Identities:
//   Alpha[i,j] = (k*q)*x_i*x_j  ->  row-softmax max = max(c*xmax, c*xmin),
//   c = k*q*x_i. All softmax/sigmoid args pre-scaled by log2(e) so exp is a
//   single v_exp_f32 (2^x). Final softmax operates on log2e-scaled o2 (scale
//   is positive-constant per row -> softmax invariant).

typedef float v2f __attribute__((ext_vector_type(2)));

#define LOG2E 1.44269504088896340736f

__device__ __forceinline__ float rcpf(float a) { return __builtin_amdgcn_rcpf(a); }

#if __has_builtin(__builtin_amdgcn_exp2f)
__device__ __forceinline__ float exp2_fast(float a) { return __builtin_amdgcn_exp2f(a); }
#else
__device__ __forceinline__ float exp2_fast(float a) { return __expf(0.6931471805599453f * a); }
#endif

__global__ __launch_bounds__(256) void fused_attn_mlp(
    const float* __restrict__ x,
    const float* __restrict__ wq,
    const float* __restrict__ wk,
    const float* __restrict__ wv,
    const float* __restrict__ Wh,
    const float* __restrict__ bh,
    const float* __restrict__ Wo,
    const float* __restrict__ bo,
    float* __restrict__ out,
    int B)
{
    // ---- stage weights into LDS (once per block) ----
    __shared__ float sWh[64 * 16];   // row-major, as given
    __shared__ float sWoT[64 * 8];   // transposed: sWoT[h*8+o] = Wo[o*64+h]
    __shared__ float sbh[64];

    const int t = threadIdx.x;
    {
        // Wh: 1024 floats = 256 float4, one per thread, coalesced
        const float4* src = reinterpret_cast<const float4*>(Wh);
        float4* dst = reinterpret_cast<float4*>(sWh);
        dst[t] = src[t];
    }
    #pragma unroll
    for (int r = t; r < 512; r += 256) {
        const int h = r >> 3, o = r & 7;
        sWoT[h * 8 + o] = Wo[o * 64 + h];
    }
    if (t < 64) sbh[t] = bh[t];
    __syncthreads();

    const int b = blockIdx.x * blockDim.x + t;
    if (b >= B) return;

    // ---- load x row: 16 floats = 4x float4 ----
    float xs[16];
    {
        const float4* xr = reinterpret_cast<const float4*>(x) + (size_t)b * 4;
        float4 a0 = xr[0], a1 = xr[1], a2 = xr[2], a3 = xr[3];
        xs[0]=a0.x; xs[1]=a0.y; xs[2]=a0.z; xs[3]=a0.w;
        xs[4]=a1.x; xs[5]=a1.y; xs[6]=a1.z; xs[7]=a1.w;
        xs[8]=a2.x; xs[9]=a2.y; xs[10]=a2.z; xs[11]=a2.w;
        xs[12]=a3.x; xs[13]=a3.y; xs[14]=a3.z; xs[15]=a3.w;
    }
    v2f xv2[8];
    #pragma unroll
    for (int p = 0; p < 8; ++p) { v2f v; v[0] = xs[2*p]; v[1] = xs[2*p+1]; xv2[p] = v; }

    // ---- attention block 1 (D=16), exp2 domain ----
    const float kq1 = wk[0] * wq[0] * LOG2E;
    const float v1  = wv[0];

    float xmx = xs[0], xmn = xs[0];
    #pragma unroll
    for (int i = 1; i < 16; ++i) { xmx = fmaxf(xmx, xs[i]); xmn = fminf(xmn, xs[i]); }

    v2f o1v[8];
    #pragma unroll
    for (int p = 0; p < 8; ++p) o1v[p] = (v2f)(0.f);

    #pragma unroll
    for (int i = 0; i < 16; ++i) {
        const float c = kq1 * xs[i];
        const float m = fmaxf(c * xmx, c * xmn);   // exact attained row max
        v2f cc; cc[0] = c; cc[1] = c;
        v2f mm; mm[0] = m; mm[1] = m;
        v2f e2[8], sv = (v2f)(0.f);
        #pragma unroll
        for (int p = 0; p < 8; ++p) {
            v2f a = cc * xv2[p] - mm;              // v_pk_fma_f32
            v2f e; e[0] = exp2_fast(a[0]); e[1] = exp2_fast(a[1]);
            e2[p] = e;
            sv += e;                                // v_pk_add_f32
        }
        const float s = sv[0] + sv[1];
        const float w = v1 * xs[i] * rcpf(s);
        v2f ww; ww[0] = w; ww[1] = w;
        #pragma unroll
        for (int p = 0; p < 8; ++p) o1v[p] += ww * e2[p];   // v_pk_fma_f32
    }

    // ---- fused MLP: 16 -> 64 sigmoid -> 8 (x1 never materialized) ----
    v2f x2v[4];
    #pragma unroll
    for (int p = 0; p < 4; ++p) { v2f v; v[0] = bo[2*p]; v[1] = bo[2*p+1]; x2v[p] = v; }

    #pragma unroll 8
    for (int h = 0; h < 64; ++h) {
        const v2f* wh = reinterpret_cast<const v2f*>(sWh + h * 16);
        v2f acc = wh[0] * o1v[0];
        #pragma unroll
        for (int p = 1; p < 8; ++p) acc += wh[p] * o1v[p];  // v_pk_fma_f32
        const float a = acc[0] + acc[1] + sbh[h];
        const float sg = rcpf(1.f + exp2_fast(-a * LOG2E)); // sigmoid
        const v2f* wo = reinterpret_cast<const v2f*>(sWoT + h * 8);
        v2f sgv; sgv[0] = sg; sgv[1] = sg;
        #pragma unroll
        for (int p = 0; p < 4; ++p) x2v[p] += wo[p] * sgv;  // v_pk_fma_f32
    }

    // ---- attention block 2 (D=8), exp2 domain; fold LOG2E into o2 for the
    //      final softmax (positive scale -> softmax invariant) ----
    const float kq2 = wk[1] * wq[1] * LOG2E;
    const float v2s = wv[1] * LOG2E;

    float ys[8];
    #pragma unroll
    for (int i = 0; i < 8; ++i) ys[i] = x2v[i >> 1][i & 1];
    float ymx = ys[0], ymn = ys[0];
    #pragma unroll
    for (int i = 1; i < 8; ++i) { ymx = fmaxf(ymx, ys[i]); ymn = fminf(ymn, ys[i]); }

    v2f o2v[4];
    #pragma unroll
    for (int p = 0; p < 4; ++p) o2v[p] = (v2f)(0.f);

    #pragma unroll
    for (int i = 0; i < 8; ++i) {
        const float c = kq2 * ys[i];
        const float m = fmaxf(c * ymx, c * ymn);
        v2f cc; cc[0] = c; cc[1] = c;
        v2f mm; mm[0] = m; mm[1] = m;
        v2f e2[4], sv = (v2f)(0.f);
        #pragma unroll
        for (int p = 0; p < 4; ++p) {
            v2f a = cc * x2v[p] - mm;
            v2f e; e[0] = exp2_fast(a[0]); e[1] = exp2_fast(a[1]);
            e2[p] = e;
            sv += e;
        }
        const float s = sv[0] + sv[1];
        const float w = v2s * ys[i] * rcpf(s);
        v2f ww; ww[0] = w; ww[1] = w;
        #pragma unroll
        for (int p = 0; p < 4; ++p) o2v[p] += ww * e2[p];
    }

    // ---- final softmax (already in log2 domain) + dot with x[8:16] ----
    float o2s[8];
    #pragma unroll
    for (int i = 0; i < 8; ++i) o2s[i] = o2v[i >> 1][i & 1];
    float m2 = o2s[0];
    #pragma unroll
    for (int i = 1; i < 8; ++i) m2 = fmaxf(m2, o2s[i]);
    float s2 = 0.f, dot = 0.f;
    #pragma unroll
    for (int i = 0; i < 8; ++i) {
        const float e = exp2_fast(o2s[i] - m2);
        s2 += e;
        dot += xs[8 + i] * e;
    }
    out[b] = dot * rcpf(s2);
}

extern "C" void kernel_launch(void* const* d_in, const int* in_sizes, int n_in,
                              void* d_out, int out_size, void* d_ws, size_t ws_size,
                              hipStream_t stream) {
    const float* x  = (const float*)d_in[0];
    const float* wq = (const float*)d_in[1];
    const float* wk = (const float*)d_in[2];
    const float* wv = (const float*)d_in[3];
    const float* Wh = (const float*)d_in[4];
    const float* bh = (const float*)d_in[5];
    const float* Wo = (const float*)d_in[6];
    const float* bo = (const float*)d_in[7];
    float* out = (float*)d_out;

    const int B = in_sizes[0] / 16;
    const int block = 256;
    const int grid = (B + block - 1) / block;
    fused_attn_mlp<<<grid, block, 0, stream>>>(x, wq, wk, wv, Wh, bh, Wo, bo, out, B);
}

// Round 3
// 127.283 us; speedup vs baseline: 1.1329x; 1.0392x over previous
//
#include <hip/hip_runtime.h>

// 2 rows per thread: two independent dependency chains interleaved per
// instruction -> hides v_exp_f32 latency that bounded round 2 (VGPR had
// collapsed to 32, serializing the transcendental pipe). Weights staged in
// LDS once per block (broadcast ds_read, shared by both rows). Packed fp32
// (v_pk_fma_f32) inner loops, exp2-domain softmax/sigmoid.
//
// Identities:
//   Alpha[i,j] = (k*q)*x_i*x_j  ->  row-softmax max = max(c*xmax, c*xmin),
//   c = k*q*x_i (exact attained max, no 16-wide scan).
//   o1[j] = v * sum_i x_i/S_i * E[i][j].

typedef float v2f __attribute__((ext_vector_type(2)));

#define LOG2E 1.44269504088896340736f
#define ROWS 2

__device__ __forceinline__ float rcpf(float a) { return __builtin_amdgcn_rcpf(a); }

#if __has_builtin(__builtin_amdgcn_exp2f)
__device__ __forceinline__ float exp2_fast(float a) { return __builtin_amdgcn_exp2f(a); }
#else
__device__ __forceinline__ float exp2_fast(float a) { return __expf(0.6931471805599453f * a); }
#endif

__global__ __launch_bounds__(256, 4) void fused_attn_mlp(
    const float* __restrict__ x,
    const float* __restrict__ wq,
    const float* __restrict__ wk,
    const float* __restrict__ wv,
    const float* __restrict__ Wh,
    const float* __restrict__ bh,
    const float* __restrict__ Wo,
    const float* __restrict__ bo,
    float* __restrict__ out,
    int B)
{
    // ---- stage weights into LDS (once per block) ----
    __shared__ float sWh[64 * 16];   // row-major as given
    __shared__ float sWoT[64 * 8];   // sWoT[h*8+o] = Wo[o*64+h]
    __shared__ float sbh[64];

    const int t = threadIdx.x;
    {
        const float4* src = reinterpret_cast<const float4*>(Wh);
        float4* dst = reinterpret_cast<float4*>(sWh);
        dst[t] = src[t];              // 256 float4 = 1024 floats, coalesced
    }
    #pragma unroll
    for (int r = t; r < 512; r += 256) {
        const int h = r >> 3, o = r & 7;
        sWoT[h * 8 + o] = Wo[o * 64 + h];
    }
    if (t < 64) sbh[t] = bh[t];
    __syncthreads();

    // rows handled: b0 + r*256 (consecutive lanes -> consecutive rows, coalesced)
    const int b0 = blockIdx.x * (256 * ROWS) + t;
    bool valid[ROWS];
    #pragma unroll
    for (int r = 0; r < ROWS; ++r) valid[r] = (b0 + r * 256) < B;

    // ---- load x rows ----
    float xs[ROWS][16];
    v2f xv2[ROWS][8];
    #pragma unroll
    for (int r = 0; r < ROWS; ++r) {
        if (valid[r]) {
            const float4* xr = reinterpret_cast<const float4*>(x) + (size_t)(b0 + r * 256) * 4;
            float4 a0 = xr[0], a1 = xr[1], a2 = xr[2], a3 = xr[3];
            xs[r][0]=a0.x; xs[r][1]=a0.y; xs[r][2]=a0.z; xs[r][3]=a0.w;
            xs[r][4]=a1.x; xs[r][5]=a1.y; xs[r][6]=a1.z; xs[r][7]=a1.w;
            xs[r][8]=a2.x; xs[r][9]=a2.y; xs[r][10]=a2.z; xs[r][11]=a2.w;
            xs[r][12]=a3.x; xs[r][13]=a3.y; xs[r][14]=a3.z; xs[r][15]=a3.w;
        } else {
            #pragma unroll
            for (int i = 0; i < 16; ++i) xs[r][i] = 0.f;
        }
        #pragma unroll
        for (int p = 0; p < 8; ++p) { v2f v; v[0]=xs[r][2*p]; v[1]=xs[r][2*p+1]; xv2[r][p]=v; }
    }

    // ---- attention block 1 (D=16), exp2 domain ----
    const float kq1 = wk[0] * wq[0] * LOG2E;
    const float v1  = wv[0];

    float xmx[ROWS], xmn[ROWS];
    #pragma unroll
    for (int r = 0; r < ROWS; ++r) {
        float mx = xs[r][0], mn = xs[r][0];
        #pragma unroll
        for (int i = 1; i < 16; ++i) { mx = fmaxf(mx, xs[r][i]); mn = fminf(mn, xs[r][i]); }
        xmx[r] = mx; xmn[r] = mn;
    }

    v2f o1v[ROWS][8];
    #pragma unroll
    for (int r = 0; r < ROWS; ++r)
        #pragma unroll
        for (int p = 0; p < 8; ++p) o1v[r][p] = (v2f)(0.f);

    #pragma unroll
    for (int i = 0; i < 16; ++i) {
        v2f e2[ROWS][8];
        float w[ROWS];
        #pragma unroll
        for (int r = 0; r < ROWS; ++r) {
            const float c = kq1 * xs[r][i];
            const float m = fmaxf(c * xmx[r], c * xmn[r]);
            v2f cc; cc[0]=c; cc[1]=c;
            v2f mm; mm[0]=m; mm[1]=m;
            v2f sv = (v2f)(0.f);
            #pragma unroll
            for (int p = 0; p < 8; ++p) {
                v2f a = cc * xv2[r][p] - mm;       // v_pk_fma_f32
                v2f e; e[0] = exp2_fast(a[0]); e[1] = exp2_fast(a[1]);
                e2[r][p] = e;
                sv += e;
            }
            w[r] = v1 * xs[r][i] * rcpf(sv[0] + sv[1]);
        }
        #pragma unroll
        for (int r = 0; r < ROWS; ++r) {
            v2f ww; ww[0]=w[r]; ww[1]=w[r];
            #pragma unroll
            for (int p = 0; p < 8; ++p) o1v[r][p] += ww * e2[r][p];
        }
    }

    // ---- fused MLP: 16 -> 64 sigmoid -> 8 (x1 never materialized) ----
    v2f x2v[ROWS][4];
    #pragma unroll
    for (int r = 0; r < ROWS; ++r)
        #pragma unroll
        for (int p = 0; p < 4; ++p) { v2f v; v[0]=bo[2*p]; v[1]=bo[2*p+1]; x2v[r][p]=v; }

    #pragma unroll 4
    for (int h = 0; h < 64; ++h) {
        const v2f* wh = reinterpret_cast<const v2f*>(sWh + h * 16);
        v2f whr[8];
        #pragma unroll
        for (int p = 0; p < 8; ++p) whr[p] = wh[p];          // one broadcast read, both rows use it
        float sg[ROWS];
        #pragma unroll
        for (int r = 0; r < ROWS; ++r) {
            v2f acc = whr[0] * o1v[r][0];
            #pragma unroll
            for (int p = 1; p < 8; ++p) acc += whr[p] * o1v[r][p];
            const float a = acc[0] + acc[1] + sbh[h];
            sg[r] = rcpf(1.f + exp2_fast(-a * LOG2E));       // sigmoid
        }
        const v2f* wo = reinterpret_cast<const v2f*>(sWoT + h * 8);
        v2f wor[4];
        #pragma unroll
        for (int p = 0; p < 4; ++p) wor[p] = wo[p];
        #pragma unroll
        for (int r = 0; r < ROWS; ++r) {
            v2f sgv; sgv[0]=sg[r]; sgv[1]=sg[r];
            #pragma unroll
            for (int p = 0; p < 4; ++p) x2v[r][p] += wor[p] * sgv;
        }
    }

    // ---- attention block 2 (D=8), exp2 domain; LOG2E folded into o2
    //      (positive per-row constant scale -> final softmax invariant) ----
    const float kq2 = wk[1] * wq[1] * LOG2E;
    const float v2s = wv[1] * LOG2E;

    float ys[ROWS][8];
    float ymx[ROWS], ymn[ROWS];
    #pragma unroll
    for (int r = 0; r < ROWS; ++r) {
        #pragma unroll
        for (int i = 0; i < 8; ++i) ys[r][i] = x2v[r][i >> 1][i & 1];
        float mx = ys[r][0], mn = ys[r][0];
        #pragma unroll
        for (int i = 1; i < 8; ++i) { mx = fmaxf(mx, ys[r][i]); mn = fminf(mn, ys[r][i]); }
        ymx[r] = mx; ymn[r] = mn;
    }

    v2f o2v[ROWS][4];
    #pragma unroll
    for (int r = 0; r < ROWS; ++r)
        #pragma unroll
        for (int p = 0; p < 4; ++p) o2v[r][p] = (v2f)(0.f);

    #pragma unroll
    for (int i = 0; i < 8; ++i) {
        v2f e2[ROWS][4];
        float w[ROWS];
        #pragma unroll
        for (int r = 0; r < ROWS; ++r) {
            const float c = kq2 * ys[r][i];
            const float m = fmaxf(c * ymx[r], c * ymn[r]);
            v2f cc; cc[0]=c; cc[1]=c;
            v2f mm; mm[0]=m; mm[1]=m;
            v2f sv = (v2f)(0.f);
            #pragma unroll
            for (int p = 0; p < 4; ++p) {
                v2f a = cc * x2v[r][p] - mm;
                v2f e; e[0] = exp2_fast(a[0]); e[1] = exp2_fast(a[1]);
                e2[r][p] = e;
                sv += e;
            }
            w[r] = v2s * ys[r][i] * rcpf(sv[0] + sv[1]);
        }
        #pragma unroll
        for (int r = 0; r < ROWS; ++r) {
            v2f ww; ww[0]=w[r]; ww[1]=w[r];
            #pragma unroll
            for (int p = 0; p < 4; ++p) o2v[r][p] += ww * e2[r][p];
        }
    }

    // ---- final softmax (log2 domain) + dot with x[8:16] ----
    #pragma unroll
    for (int r = 0; r < ROWS; ++r) {
        float o2s[8];
        #pragma unroll
        for (int i = 0; i < 8; ++i) o2s[i] = o2v[r][i >> 1][i & 1];
        float m2 = o2s[0];
        #pragma unroll
        for (int i = 1; i < 8; ++i) m2 = fmaxf(m2, o2s[i]);
        float s2 = 0.f, dot = 0.f;
        #pragma unroll
        for (int i = 0; i < 8; ++i) {
            const float e = exp2_fast(o2s[i] - m2);
            s2 += e;
            dot += xs[r][8 + i] * e;
        }
        if (valid[r]) out[b0 + r * 256] = dot * rcpf(s2);
    }
}

extern "C" void kernel_launch(void* const* d_in, const int* in_sizes, int n_in,
                              void* d_out, int out_size, void* d_ws, size_t ws_size,
                              hipStream_t stream) {
    const float* x  = (const float*)d_in[0];
    const float* wq = (const float*)d_in[1];
    const float* wk = (const float*)d_in[2];
    const float* wv = (const float*)d_in[3];
    const float* Wh = (const float*)d_in[4];
    const float* bh = (const float*)d_in[5];
    const float* Wo = (const float*)d_in[6];
    const float* bo = (const float*)d_in[7];
    float* out = (float*)d_out;

    const int B = in_sizes[0] / 16;
    const int block = 256;
    const int rows_per_block = block * ROWS;
    const int grid = (B + rows_per_block - 1) / rows_per_block;
    fused_attn_mlp<<<grid, block, 0, stream>>>(x, wq, wk, wv, Wh, bh, Wo, bo, out, B);
}